// Round 1
// baseline (237.109 us; speedup 1.0000x reference)
//
#include <hip/hip_runtime.h>
#include <hip/hip_fp16.h>
#include <math.h>

#define LEAKY 0.2f
#define HDIM 64
#define EPB 2048            // edges per block (fused)
#define TPB1 256
#define PERT (EPB / TPB1)   // 8 edges per thread
#define RANGE 1024          // nodes per bucket
#define RSH 10
#define KMAX 128
#define NSLICE 12
#define FIXS 4194304.0f     // 2^22 fixed-point scale
#define INVFIXS (1.0f / 4194304.0f)

// record: bits [0,11) lid, [11,27) f16 mx, [27,43) f16 my, [43,59) f16 mz

// tanh(v) = 1 - 2/(exp2(v*2*log2e)+1); exact saturation, ~1e-6 rel err (R10/11-verified)
__device__ __forceinline__ float fast_tanh(float v) {
    float e = __builtin_amdgcn_exp2f(v * 2.88539008178f);
    return 1.0f - 2.0f * __builtin_amdgcn_rcpf(e + 1.0f);
}

__device__ __forceinline__ float edge_eo(float rad, float C, bool slow,
                                         const float* sW1, const float* sb1,
                                         const float* sW2) {
    if (!slow) return fast_tanh(C * rad);  // bp1==0, rad>=0: MLP collapses to linear
    float a = 0.f;
    #pragma unroll
    for (int k = 0; k < HDIM; k++) {
        float h = fmaf(rad, sW1[k], sb1[k]);
        h = (h > 0.f) ? h : LEAKY * h;
        a = fmaf(sW2[k], h, a);
    }
    return fast_tanh(a);
}

// half-packed coords + consts precompute + acc/cursor zero-init (all in one dispatch)
__global__ void repack_h_kernel(const float* __restrict__ x, uint2* __restrict__ xh, int N,
                                const float* __restrict__ Wp1, const float* __restrict__ bp1,
                                const float* __restrict__ Wp2, float* __restrict__ consts,
                                uint4* __restrict__ acc4, unsigned* __restrict__ cursor, int K) {
    int i = blockIdx.x * blockDim.x + threadIdx.x;
    if (i < N) {
        unsigned hx = __half_as_ushort(__float2half(x[3*i]));
        unsigned hy = __half_as_ushort(__float2half(x[3*i+1]));
        unsigned hz = __half_as_ushort(__float2half(x[3*i+2]));
        xh[i] = make_uint2((hy << 16) | hx, hz);
        acc4[i] = make_uint4(0u, 0u, 0u, 0u);
    }
    if (blockIdx.x == 0) {
        if (threadIdx.x < 64) {
            int k = threadIdx.x;   // one wave: shuffle reduction valid
            float w1 = Wp1[k];
            float slope = (w1 >= 0.f) ? 1.f : LEAKY;
            float c = Wp2[k] * w1 * slope;
            float bnz = (bp1[k] != 0.f) ? 1.f : 0.f;
            #pragma unroll
            for (int off = 32; off > 0; off >>= 1) {
                c += __shfl_down(c, off, 64);
                bnz += __shfl_down(bnz, off, 64);
            }
            if (k == 0) { consts[0] = c; consts[1] = bnz; }
        }
        if ((int)threadIdx.x < K) cursor[threadIdx.x] = 0u;
    }
}

__device__ __forceinline__ unsigned long long pack_rec(float dx, float dy, float dz,
                                                       float eo, unsigned lid) {
    unsigned hx = __half_as_ushort(__float2half(dx * eo));
    unsigned hy = __half_as_ushort(__float2half(dy * eo));
    unsigned hz = __half_as_ushort(__float2half(dz * eo));
    return (unsigned long long)lid
         | ((unsigned long long)hx << 11)
         | ((unsigned long long)hy << 27)
         | ((unsigned long long)hz << 43);
}

__device__ __forceinline__ uint2 make_record(uint2 ga, uint2 gb, int r,
                                             float C, bool slow,
                                             const float* sW1, const float* sb1,
                                             const float* sW2) {
    float ax = __half2float(__ushort_as_half((unsigned short)(ga.x & 0xFFFF)));
    float ay = __half2float(__ushort_as_half((unsigned short)(ga.x >> 16)));
    float az = __half2float(__ushort_as_half((unsigned short)(ga.y & 0xFFFF)));
    float bx = __half2float(__ushort_as_half((unsigned short)(gb.x & 0xFFFF)));
    float by = __half2float(__ushort_as_half((unsigned short)(gb.x >> 16)));
    float bz = __half2float(__ushort_as_half((unsigned short)(gb.y & 0xFFFF)));
    float dx = ax - bx, dy = ay - by, dz = az - bz;
    float rad = sqrtf(dx*dx + dy*dy + dz*dz);
    float eo = edge_eo(rad, C, slow, sW1, sb1, sW2);
    unsigned long long u = pack_rec(dx, dy, dz, eo, (unsigned)r & (RANGE - 1));
    return make_uint2((unsigned)u, (unsigned)(u >> 32));
}

// direct fixed-point atomic fallback for a packed record (used on bucket overflow)
__device__ __forceinline__ void rec_to_acc4(uint2 r, unsigned b_, unsigned* acc4) {
    unsigned long long u = ((unsigned long long)r.y << 32) | r.x;
    unsigned lid = (unsigned)(u & (RANGE - 1));
    unsigned node = b_ * RANGE + lid;
    float mx = __half2float(__ushort_as_half((unsigned short)((u >> 11) & 0xFFFF)));
    float my = __half2float(__ushort_as_half((unsigned short)((u >> 27) & 0xFFFF)));
    float mz = __half2float(__ushort_as_half((unsigned short)((u >> 43) & 0xFFFF)));
    atomicAdd(&acc4[4*node + 0], (unsigned)(int)__float2int_rn(mx * FIXS));
    atomicAdd(&acc4[4*node + 1], (unsigned)(int)__float2int_rn(my * FIXS));
    atomicAdd(&acc4[4*node + 2], (unsigned)(int)__float2int_rn(mz * FIXS));
    atomicAdd(&acc4[4*node + 3], 1u);
}

// ---- FUSED compute+sort, cursor-reservation version (no count pass, no colscan)
// Reduce is a commutative fixed-point sum, so within-bucket record order is
// irrelevant -> per-(block,bucket) global cursor atomics give identical output.
// Bucket b owns recs[b*cap .. b*cap+cap); overflow (never in practice, cap has
// ~16-sigma margin) degrades gracefully to direct fixed-point atomics.
__global__ __launch_bounds__(TPB1) void fused3_kernel(
        const uint2* __restrict__ xh,
        const int* __restrict__ ei,
        const float* __restrict__ Wp1, const float* __restrict__ bp1,
        const float* __restrict__ Wp2, const float* __restrict__ consts,
        unsigned* __restrict__ cursor, unsigned* __restrict__ acc4,
        uint2* __restrict__ recs, int E, int K, unsigned cap) {
    __shared__ uint2 stage[EPB];                 // 16 KB
    __shared__ unsigned char bucket_of[EPB];     // 2 KB
    __shared__ unsigned hist[KMAX];
    __shared__ unsigned scanv[KMAX + 1];
    __shared__ unsigned gstart[KMAX];
    __shared__ float sW1[HDIM], sb1[HDIM], sW2[HDIM];
    const float C = consts[0];
    const bool slow = (consts[1] != 0.f);
    if (slow) {
        for (int k = threadIdx.x; k < HDIM; k += TPB1) {
            sW1[k] = Wp1[k]; sb1[k] = bp1[k]; sW2[k] = Wp2[k];
        }
    }
    for (int k = threadIdx.x; k < K; k += TPB1) hist[k] = 0;
    __syncthreads();

    const size_t base = (size_t)blockIdx.x * EPB;
    const unsigned t = threadIdx.x;
    uint2 rc[PERT];
    unsigned bk[PERT];
    if (base + EPB <= (size_t)E && (E & 3) == 0) {
        const int4* pr = (const int4*)(ei + base);
        const int4* pc = (const int4*)(ei + (size_t)E + base);
        // two index quads, then ALL 16 gathers in flight before first use (MLP)
        int4 rv0 = pr[t];
        int4 rv1 = pr[t + TPB1];
        int4 cv0 = pc[t];
        int4 cv1 = pc[t + TPB1];
        uint2 ga0 = xh[rv0.x], ga1 = xh[rv0.y], ga2 = xh[rv0.z], ga3 = xh[rv0.w];
        uint2 ga4 = xh[rv1.x], ga5 = xh[rv1.y], ga6 = xh[rv1.z], ga7 = xh[rv1.w];
        uint2 gb0 = xh[cv0.x], gb1 = xh[cv0.y], gb2 = xh[cv0.z], gb3 = xh[cv0.w];
        uint2 gb4 = xh[cv1.x], gb5 = xh[cv1.y], gb6 = xh[cv1.z], gb7 = xh[cv1.w];
        rc[0] = make_record(ga0, gb0, rv0.x, C, slow, sW1, sb1, sW2);
        rc[1] = make_record(ga1, gb1, rv0.y, C, slow, sW1, sb1, sW2);
        rc[2] = make_record(ga2, gb2, rv0.z, C, slow, sW1, sb1, sW2);
        rc[3] = make_record(ga3, gb3, rv0.w, C, slow, sW1, sb1, sW2);
        rc[4] = make_record(ga4, gb4, rv1.x, C, slow, sW1, sb1, sW2);
        rc[5] = make_record(ga5, gb5, rv1.y, C, slow, sW1, sb1, sW2);
        rc[6] = make_record(ga6, gb6, rv1.z, C, slow, sW1, sb1, sW2);
        rc[7] = make_record(ga7, gb7, rv1.w, C, slow, sW1, sb1, sW2);
        bk[0] = (unsigned)rv0.x >> RSH; bk[1] = (unsigned)rv0.y >> RSH;
        bk[2] = (unsigned)rv0.z >> RSH; bk[3] = (unsigned)rv0.w >> RSH;
        bk[4] = (unsigned)rv1.x >> RSH; bk[5] = (unsigned)rv1.y >> RSH;
        bk[6] = (unsigned)rv1.z >> RSH; bk[7] = (unsigned)rv1.w >> RSH;
        #pragma unroll
        for (int i = 0; i < PERT; i++) atomicAdd(&hist[bk[i]], 1u);
    } else {
        #pragma unroll
        for (int i = 0; i < PERT; i++) {
            size_t e = base + (size_t)i * TPB1 + t;
            bk[i] = 0xFFFFFFFFu;
            if (e < (size_t)E) {
                int r = ei[e];
                int c = ei[(size_t)E + e];
                uint2 ga = xh[r], gb = xh[c];
                rc[i] = make_record(ga, gb, r, C, slow, sW1, sb1, sW2);
                bk[i] = (unsigned)r >> RSH;
                atomicAdd(&hist[bk[i]], 1u);
            }
        }
    }
    __syncthreads();
    // serial local scan (R7-verified)
    if (t == 0) {
        unsigned a = 0;
        for (int k = 0; k < K; k++) { scanv[k] = a; a += hist[k]; }
        scanv[K] = a;
    }
    __syncthreads();
    // reserve this block's per-bucket segment with one global atomic each
    if (t < (unsigned)K) {
        unsigned c_ = scanv[t + 1] - scanv[t];
        gstart[t] = c_ ? atomicAdd(&cursor[t], c_) : 0u;
    }
    for (int k = t; k < K; k += TPB1) hist[k] = scanv[k];  // running cursors
    __syncthreads();
    // phase-2 scatter into stage (R5-verified rank atomic)
    #pragma unroll
    for (int i = 0; i < PERT; i++) {
        if (bk[i] != 0xFFFFFFFFu) {
            unsigned slot = atomicAdd(&hist[bk[i]], 1u);
            stage[slot] = rc[i];
            bucket_of[slot] = (unsigned char)bk[i];
        }
    }
    __syncthreads();
    // coalesced write-out into fixed-capacity bucket regions
    unsigned total = scanv[K];
    for (unsigned j = t; j < total; j += TPB1) {
        unsigned b_ = bucket_of[j];
        unsigned off = gstart[b_] + (j - scanv[b_]);
        if (off < cap) recs[(size_t)b_ * cap + off] = stage[j];
        else           rec_to_acc4(stage[j], b_, acc4);   // overflow: direct atomics
    }
}

__device__ __forceinline__ void proc_rec(uint2 r, unsigned (*acc)[RANGE]) {
    unsigned long long u = ((unsigned long long)r.y << 32) | r.x;
    unsigned lid = (unsigned)(u & (RANGE - 1));
    float mx = __half2float(__ushort_as_half((unsigned short)((u >> 11) & 0xFFFF)));
    float my = __half2float(__ushort_as_half((unsigned short)((u >> 27) & 0xFFFF)));
    float mz = __half2float(__ushort_as_half((unsigned short)((u >> 43) & 0xFFFF)));
    // fixed-point u32 atomics: fast int LDS path (round-5 verified)
    atomicAdd(&acc[0][lid], (unsigned)(int)__float2int_rn(mx * FIXS));
    atomicAdd(&acc[1][lid], (unsigned)(int)__float2int_rn(my * FIXS));
    atomicAdd(&acc[2][lid], (unsigned)(int)__float2int_rn(mz * FIXS));
    atomicAdd(&acc[3][lid], 1u);
}

// region-based reduce: bucket b at recs[b*cap ..), count from cursor[b].
// LDS fixed-point accumulate, then 4 global u32 atomics per touched node
// (replaces the 12-slice 38 MB round-trip).
__global__ __launch_bounds__(256) void reduce3_kernel(
        const uint2* __restrict__ recs, const unsigned* __restrict__ cursor,
        unsigned* __restrict__ acc4, int N, int K, unsigned cap) {
    __shared__ unsigned acc[4][RANGE];
    int b = blockIdx.x / NSLICE;
    int s = blockIdx.x % NSLICE;
    for (int i = threadIdx.x; i < RANGE; i += 256) {
        acc[0][i] = 0u; acc[1][i] = 0u; acc[2][i] = 0u; acc[3][i] = 0u;
    }
    __syncthreads();
    unsigned cnt = cursor[b];
    if (cnt > cap) cnt = cap;          // overflow edges already in acc4 directly
    unsigned per = (cnt + NSLICE - 1) / NSLICE;
    unsigned st = (unsigned)s * per;
    unsigned en = st + per; if (en > cnt) en = cnt;
    const uint2* rb = recs + (size_t)b * cap;
    unsigned j = st + threadIdx.x;
    if (st < cnt) {
        while (j + 256 < en) {
            uint2 r0 = rb[j];
            uint2 r1 = rb[j + 256];
            proc_rec(r0, acc);
            proc_rec(r1, acc);
            j += 512;
        }
        while (j < en) { proc_rec(rb[j], acc); j += 256; }
    }
    __syncthreads();
    int nbase = b * RANGE;
    for (int i = threadIdx.x; i < RANGE; i += 256) {
        int node = nbase + i;
        if (node < N && acc[3][i] != 0u) {
            atomicAdd(&acc4[4*node + 0], acc[0][i]);
            atomicAdd(&acc4[4*node + 1], acc[1][i]);
            atomicAdd(&acc4[4*node + 2], acc[2][i]);
            atomicAdd(&acc4[4*node + 3], acc[3][i]);
        }
    }
}

// final node pass reading the fixed-point accumulator directly
__global__ void node_fixed_kernel(const float* __restrict__ x,
                                  const float* __restrict__ vel_norm,
                                  const float* __restrict__ vel,
                                  const float* __restrict__ W1, const float* __restrict__ b1,
                                  const float* __restrict__ W2, const float* __restrict__ b2,
                                  const uint4* __restrict__ acc4,
                                  float* __restrict__ out, int N) {
    __shared__ float sW1[HDIM], sb1[HDIM], sW2[HDIM];
    for (int k = threadIdx.x; k < HDIM; k += blockDim.x) {
        sW1[k] = W1[k]; sb1[k] = b1[k]; sW2[k] = W2[k];
    }
    __syncthreads();
    int i = blockIdx.x * blockDim.x + threadIdx.x;
    if (i >= N) return;
    uint4 a4 = acc4[i];
    float sx = (float)(int)a4.x * INVFIXS;
    float sy = (float)(int)a4.y * INVFIXS;
    float sz = (float)(int)a4.z * INVFIXS;
    float sc = (float)a4.w;
    float vn = vel_norm[i];
    float a = b2[0];
    #pragma unroll
    for (int k = 0; k < HDIM; k++) {
        float h = fmaf(vn, sW1[k], sb1[k]);
        h = (h > 0.f) ? h : LEAKY * h;
        a = fmaf(sW2[k], h, a);
    }
    float inv = 1.0f / fmaxf(sc, 1.0f);
    out[3*i]     = x[3*i]     + sx * inv + vel[3*i]     * a;
    out[3*i + 1] = x[3*i + 1] + sy * inv + vel[3*i + 1] * a;
    out[3*i + 2] = x[3*i + 2] + sz * inv + vel[3*i + 2] * a;
}

// ---- plain-atomic fallback path (K > KMAX or tiny workspace) ----
__global__ void precompute_kernel(const float* __restrict__ Wp1,
                                  const float* __restrict__ bp1,
                                  const float* __restrict__ Wp2,
                                  float* __restrict__ consts) {
    int k = threadIdx.x;
    float w1 = Wp1[k];
    float slope = (w1 >= 0.f) ? 1.f : LEAKY;
    float c = Wp2[k] * w1 * slope;
    float bnz = (bp1[k] != 0.f) ? 1.f : 0.f;
    #pragma unroll
    for (int off = 32; off > 0; off >>= 1) {
        c += __shfl_down(c, off, 64);
        bnz += __shfl_down(bnz, off, 64);
    }
    if (k == 0) { consts[0] = c; consts[1] = bnz; }
}

__global__ void edge_atomic_kernel(const float* __restrict__ x, const int* __restrict__ ei,
                                   const float* __restrict__ Wp1, const float* __restrict__ bp1,
                                   const float* __restrict__ Wp2, const float* __restrict__ consts,
                                   float* __restrict__ acc, int E) {
    __shared__ float sW1[HDIM], sb1[HDIM], sW2[HDIM];
    const float C = consts[0];
    const bool slow = (consts[1] != 0.f);
    if (slow) {
        for (int k = threadIdx.x; k < HDIM; k += blockDim.x) {
            sW1[k] = Wp1[k]; sb1[k] = bp1[k]; sW2[k] = Wp2[k];
        }
        __syncthreads();
    }
    int e = blockIdx.x * blockDim.x + threadIdx.x;
    if (e >= E) return;
    int r = ei[e];
    int c = ei[E + e];
    float dx = x[3*r] - x[3*c];
    float dy = x[3*r+1] - x[3*c+1];
    float dz = x[3*r+2] - x[3*c+2];
    float rad = sqrtf(dx*dx + dy*dy + dz*dz);
    float eo = edge_eo(rad, C, slow, sW1, sb1, sW2);
    float* basep = acc + ((size_t)r << 2);
    atomicAdd(basep + 0, dx * eo);
    atomicAdd(basep + 1, dy * eo);
    atomicAdd(basep + 2, dz * eo);
    atomicAdd(basep + 3, 1.f);
}

__global__ void node_kernel(const float* __restrict__ x, const float* __restrict__ vel_norm,
                            const float* __restrict__ vel,
                            const float* __restrict__ W1, const float* __restrict__ b1,
                            const float* __restrict__ W2, const float* __restrict__ b2,
                            const float4* __restrict__ slices,
                            float* __restrict__ out, int N, int S) {
    __shared__ float sW1[HDIM], sb1[HDIM], sW2[HDIM];
    for (int k = threadIdx.x; k < HDIM; k += blockDim.x) {
        sW1[k] = W1[k]; sb1[k] = b1[k]; sW2[k] = W2[k];
    }
    __syncthreads();
    int i = blockIdx.x * blockDim.x + threadIdx.x;
    if (i >= N) return;
    float sx = 0.f, sy = 0.f, sz = 0.f, sc = 0.f;
    for (int s = 0; s < S; s++) {
        float4 v = slices[(size_t)s * N + i];
        sx += v.x; sy += v.y; sz += v.z; sc += v.w;
    }
    float vn = vel_norm[i];
    float a = b2[0];
    #pragma unroll
    for (int k = 0; k < HDIM; k++) {
        float h = fmaf(vn, sW1[k], sb1[k]);
        h = (h > 0.f) ? h : LEAKY * h;
        a = fmaf(sW2[k], h, a);
    }
    float inv = 1.0f / fmaxf(sc, 1.0f);
    out[3*i]     = x[3*i]     + sx * inv + vel[3*i]     * a;
    out[3*i + 1] = x[3*i + 1] + sy * inv + vel[3*i + 1] * a;
    out[3*i + 2] = x[3*i + 2] + sz * inv + vel[3*i + 2] * a;
}

extern "C" void kernel_launch(void* const* d_in, const int* in_sizes, int n_in,
                              void* d_out, int out_size, void* d_ws, size_t ws_size,
                              hipStream_t stream) {
    const float* x        = (const float*)d_in[0];
    const float* vel_norm = (const float*)d_in[1];
    const float* vel      = (const float*)d_in[2];
    const int*   ei       = (const int*)  d_in[3];
    const float* W1       = (const float*)d_in[4];
    const float* b1       = (const float*)d_in[5];
    const float* W2       = (const float*)d_in[6];
    const float* b2       = (const float*)d_in[7];
    const float* Wp1      = (const float*)d_in[8];
    const float* bp1      = (const float*)d_in[9];
    const float* Wp2      = (const float*)d_in[10];

    const int N = in_sizes[0] / 3;
    const int E = in_sizes[3] / 2;
    const int K = (N + RANGE - 1) / RANGE;
    const int nblk = (E + EPB - 1) / EPB;

    // fixed bucket capacity: mean + 8192 (~16 sigma for uniform-random rows);
    // overflow degrades to direct atomics, so cap only affects speed, not correctness
    unsigned cap = (unsigned)((E + K - 1) / K) + 8192u;
    cap = (cap + 63u) & ~63u;

    // layout: [recs: K*cap*8] [xh: N*8] [acc4: N*16] [cursor: KMAX*4] [consts]
    size_t sp_xh    = (size_t)K * cap * sizeof(uint2);
    size_t sp_acc   = (sp_xh + (size_t)N * sizeof(uint2) + 15) & ~(size_t)15;
    size_t sp_cur   = sp_acc + (size_t)N * sizeof(uint4);
    size_t sp_const = (sp_cur + (size_t)KMAX * sizeof(unsigned) + 15) & ~(size_t)15;
    size_t need     = sp_const + 32;

    if (K <= KMAX && ws_size >= need) {
        uint2*    recs   = (uint2*)   d_ws;
        uint2*    xh     = (uint2*)   ((char*)d_ws + sp_xh);
        unsigned* acc4   = (unsigned*)((char*)d_ws + sp_acc);
        unsigned* cursor = (unsigned*)((char*)d_ws + sp_cur);
        float*    consts = (float*)   ((char*)d_ws + sp_const);

        repack_h_kernel<<<(N + 255) / 256, 256, 0, stream>>>(
            x, xh, N, Wp1, bp1, Wp2, consts, (uint4*)acc4, cursor, K);
        fused3_kernel<<<nblk, TPB1, 0, stream>>>(
            xh, ei, Wp1, bp1, Wp2, consts, cursor, acc4, recs, E, K, cap);
        reduce3_kernel<<<K * NSLICE, 256, 0, stream>>>(recs, cursor, acc4, N, K, cap);
        node_fixed_kernel<<<(N + 255) / 256, 256, 0, stream>>>(
            x, vel_norm, vel, W1, b1, W2, b2, (const uint4*)acc4, (float*)d_out, N);
    } else {
        float* acc    = (float*)d_ws;
        float* consts = (float*)((char*)d_ws + (size_t)N * sizeof(float4));
        hipMemsetAsync(d_ws, 0, (size_t)N * sizeof(float4) + 32, stream);
        precompute_kernel<<<1, 64, 0, stream>>>(Wp1, bp1, Wp2, consts);
        edge_atomic_kernel<<<(E + 255) / 256, 256, 0, stream>>>(x, ei, Wp1, bp1, Wp2,
                                                                consts, acc, E);
        node_kernel<<<(N + 255) / 256, 256, 0, stream>>>(x, vel_norm, vel, W1, b1, W2, b2,
                                                         (const float4*)acc, (float*)d_out, N, 1);
    }
}

// Round 2
// 189.404 us; speedup vs baseline: 1.2519x; 1.2519x over previous
//
#include <hip/hip_runtime.h>
#include <hip/hip_fp16.h>
#include <math.h>

#define LEAKY 0.2f
#define HDIM 64
#define EPB 2048            // edges per block (fused)
#define TPB1 256
#define PERT (EPB / TPB1)   // 8 edges per thread
#define RANGE 1024          // nodes per bucket
#define RSH 10
#define KMAX 128
#define NSUB 4              // sub-cursors per bucket (contention mitigation)
#define NSLICE 8            // reduce slices per bucket = NSUB * 2
#define FS2 262144.0f       // 2^18 fixed-point scale
#define INVFS2 (1.0f / 262144.0f)
#define FBIAS 4194304       // 2^22 per-record field bias (keeps packed u32 fields non-negative)

// record: bits [0,11) lid, [11,27) f16 mx, [27,43) f16 my, [43,59) f16 mz

// tanh(v) = 1 - 2/(exp2(v*2*log2e)+1); exact saturation, ~1e-6 rel err (R10/11-verified)
__device__ __forceinline__ float fast_tanh(float v) {
    float e = __builtin_amdgcn_exp2f(v * 2.88539008178f);
    return 1.0f - 2.0f * __builtin_amdgcn_rcpf(e + 1.0f);
}

__device__ __forceinline__ float edge_eo(float rad, float C, bool slow,
                                         const float* sW1, const float* sb1,
                                         const float* sW2) {
    if (!slow) return fast_tanh(C * rad);  // bp1==0, rad>=0: MLP collapses to linear
    float a = 0.f;
    #pragma unroll
    for (int k = 0; k < HDIM; k++) {
        float h = fmaf(rad, sW1[k], sb1[k]);
        h = (h > 0.f) ? h : LEAKY * h;
        a = fmaf(sW2[k], h, a);
    }
    return fast_tanh(a);
}

// half-packed coords + consts precompute + acc4/cursor zero-init (one dispatch)
__global__ void repack_h_kernel(const float* __restrict__ x, uint2* __restrict__ xh, int N,
                                const float* __restrict__ Wp1, const float* __restrict__ bp1,
                                const float* __restrict__ Wp2, float* __restrict__ consts,
                                uint4* __restrict__ acc4, unsigned* __restrict__ cursor, int K) {
    int i = blockIdx.x * blockDim.x + threadIdx.x;
    if (i < N) {
        unsigned hx = __half_as_ushort(__float2half(x[3*i]));
        unsigned hy = __half_as_ushort(__float2half(x[3*i+1]));
        unsigned hz = __half_as_ushort(__float2half(x[3*i+2]));
        xh[i] = make_uint2((hy << 16) | hx, hz);
        acc4[i] = make_uint4(0u, 0u, 0u, 0u);
    }
    if (blockIdx.x == 0) {
        if (threadIdx.x < 64) {
            int k = threadIdx.x;   // one wave: shuffle reduction valid
            float w1 = Wp1[k];
            float slope = (w1 >= 0.f) ? 1.f : LEAKY;
            float c = Wp2[k] * w1 * slope;
            float bnz = (bp1[k] != 0.f) ? 1.f : 0.f;
            #pragma unroll
            for (int off = 32; off > 0; off >>= 1) {
                c += __shfl_down(c, off, 64);
                bnz += __shfl_down(bnz, off, 64);
            }
            if (k == 0) { consts[0] = c; consts[1] = bnz; }
        }
        for (int k = threadIdx.x; k < NSUB * K; k += 256) cursor[k] = 0u;
    }
}

__device__ __forceinline__ unsigned long long pack_rec(float dx, float dy, float dz,
                                                       float eo, unsigned lid) {
    unsigned hx = __half_as_ushort(__float2half(dx * eo));
    unsigned hy = __half_as_ushort(__float2half(dy * eo));
    unsigned hz = __half_as_ushort(__float2half(dz * eo));
    return (unsigned long long)lid
         | ((unsigned long long)hx << 11)
         | ((unsigned long long)hy << 27)
         | ((unsigned long long)hz << 43);
}

__device__ __forceinline__ uint2 make_record(uint2 ga, uint2 gb, int r,
                                             float C, bool slow,
                                             const float* sW1, const float* sb1,
                                             const float* sW2) {
    float ax = __half2float(__ushort_as_half((unsigned short)(ga.x & 0xFFFF)));
    float ay = __half2float(__ushort_as_half((unsigned short)(ga.x >> 16)));
    float az = __half2float(__ushort_as_half((unsigned short)(ga.y & 0xFFFF)));
    float bx = __half2float(__ushort_as_half((unsigned short)(gb.x & 0xFFFF)));
    float by = __half2float(__ushort_as_half((unsigned short)(gb.x >> 16)));
    float bz = __half2float(__ushort_as_half((unsigned short)(gb.y & 0xFFFF)));
    float dx = ax - bx, dy = ay - by, dz = az - bz;
    float rad = sqrtf(dx*dx + dy*dy + dz*dz);
    float eo = edge_eo(rad, C, slow, sW1, sb1, sW2);
    unsigned long long u = pack_rec(dx, dy, dz, eo, (unsigned)r & (RANGE - 1));
    return make_uint2((unsigned)u, (unsigned)(u >> 32));
}

// direct fixed-point global-atomic fallback for a packed record (bucket overflow only;
// unbiased signed 2^18 fixed — two's-complement wrap makes separate u32 adds exact)
__device__ __forceinline__ void rec_to_acc4(uint2 r, unsigned b_, unsigned* acc4) {
    unsigned long long u = ((unsigned long long)r.y << 32) | r.x;
    unsigned lid = (unsigned)(u & (RANGE - 1));
    unsigned node = b_ * RANGE + lid;
    float mx = __half2float(__ushort_as_half((unsigned short)((u >> 11) & 0xFFFF)));
    float my = __half2float(__ushort_as_half((unsigned short)((u >> 27) & 0xFFFF)));
    float mz = __half2float(__ushort_as_half((unsigned short)((u >> 43) & 0xFFFF)));
    atomicAdd(&acc4[4*node + 0], (unsigned)__float2int_rn(mx * FS2));
    atomicAdd(&acc4[4*node + 1], (unsigned)__float2int_rn(my * FS2));
    atomicAdd(&acc4[4*node + 2], (unsigned)__float2int_rn(mz * FS2));
    atomicAdd(&acc4[4*node + 3], 1u);
}

// ---- FUSED compute+sort with sub-cursor reservation.
// Reservation atomic issued right after the histogram; its return is consumed only
// after the scatter phase (overlapped with the wave-3 shuffle scan + LDS scatter).
// 4 sub-cursors per bucket cut the same-address chain depth 4x. Records for
// (bucket b, sub r) live at recs[((b*4+r)*csub) ..); overflow -> direct atomics.
__global__ __launch_bounds__(TPB1) void fused4_kernel(
        const uint2* __restrict__ xh,
        const int* __restrict__ ei,
        const float* __restrict__ Wp1, const float* __restrict__ bp1,
        const float* __restrict__ Wp2, const float* __restrict__ consts,
        unsigned* __restrict__ cursor, unsigned* __restrict__ acc4,
        uint2* __restrict__ recs, int E, int K, unsigned csub) {
    __shared__ uint2 stage[EPB];                 // 16 KB
    __shared__ unsigned char bucket_of[EPB];     // 2 KB
    __shared__ unsigned hist[KMAX];
    __shared__ unsigned scanv[KMAX + 1];
    __shared__ unsigned gstart[KMAX];
    __shared__ float sW1[HDIM], sb1[HDIM], sW2[HDIM];
    const float C = consts[0];
    const bool slow = (consts[1] != 0.f);
    const unsigned sub = (unsigned)blockIdx.x & (NSUB - 1);
    if (slow) {
        for (int k = threadIdx.x; k < HDIM; k += TPB1) {
            sW1[k] = Wp1[k]; sb1[k] = bp1[k]; sW2[k] = Wp2[k];
        }
    }
    for (int k = threadIdx.x; k < K; k += TPB1) hist[k] = 0;
    __syncthreads();

    const size_t base = (size_t)blockIdx.x * EPB;
    const unsigned t = threadIdx.x;
    uint2 rc[PERT];
    unsigned bk[PERT];
    if (base + EPB <= (size_t)E && (E & 3) == 0) {
        const int4* pr = (const int4*)(ei + base);
        const int4* pc = (const int4*)(ei + (size_t)E + base);
        // two index quads, then ALL 16 gathers in flight before first use (MLP)
        int4 rv0 = pr[t];
        int4 rv1 = pr[t + TPB1];
        int4 cv0 = pc[t];
        int4 cv1 = pc[t + TPB1];
        uint2 ga0 = xh[rv0.x], ga1 = xh[rv0.y], ga2 = xh[rv0.z], ga3 = xh[rv0.w];
        uint2 ga4 = xh[rv1.x], ga5 = xh[rv1.y], ga6 = xh[rv1.z], ga7 = xh[rv1.w];
        uint2 gb0 = xh[cv0.x], gb1 = xh[cv0.y], gb2 = xh[cv0.z], gb3 = xh[cv0.w];
        uint2 gb4 = xh[cv1.x], gb5 = xh[cv1.y], gb6 = xh[cv1.z], gb7 = xh[cv1.w];
        rc[0] = make_record(ga0, gb0, rv0.x, C, slow, sW1, sb1, sW2);
        rc[1] = make_record(ga1, gb1, rv0.y, C, slow, sW1, sb1, sW2);
        rc[2] = make_record(ga2, gb2, rv0.z, C, slow, sW1, sb1, sW2);
        rc[3] = make_record(ga3, gb3, rv0.w, C, slow, sW1, sb1, sW2);
        rc[4] = make_record(ga4, gb4, rv1.x, C, slow, sW1, sb1, sW2);
        rc[5] = make_record(ga5, gb5, rv1.y, C, slow, sW1, sb1, sW2);
        rc[6] = make_record(ga6, gb6, rv1.z, C, slow, sW1, sb1, sW2);
        rc[7] = make_record(ga7, gb7, rv1.w, C, slow, sW1, sb1, sW2);
        bk[0] = (unsigned)rv0.x >> RSH; bk[1] = (unsigned)rv0.y >> RSH;
        bk[2] = (unsigned)rv0.z >> RSH; bk[3] = (unsigned)rv0.w >> RSH;
        bk[4] = (unsigned)rv1.x >> RSH; bk[5] = (unsigned)rv1.y >> RSH;
        bk[6] = (unsigned)rv1.z >> RSH; bk[7] = (unsigned)rv1.w >> RSH;
        #pragma unroll
        for (int i = 0; i < PERT; i++) atomicAdd(&hist[bk[i]], 1u);
    } else {
        #pragma unroll
        for (int i = 0; i < PERT; i++) {
            size_t e = base + (size_t)i * TPB1 + t;
            bk[i] = 0xFFFFFFFFu;
            if (e < (size_t)E) {
                int r = ei[e];
                int c = ei[(size_t)E + e];
                uint2 ga = xh[r], gb = xh[c];
                rc[i] = make_record(ga, gb, r, C, slow, sW1, sb1, sW2);
                bk[i] = (unsigned)r >> RSH;
                atomicAdd(&hist[bk[i]], 1u);
            }
        }
    }
    __syncthreads();   // B1: hist complete
    // issue reservation immediately (waves 0-1); return consumed only after scatter
    unsigned res = 0, myc = 0;
    if (t < (unsigned)K) {
        myc = hist[t];
        if (myc) res = atomicAdd(&cursor[t * NSUB + sub], myc);
    }
    // wave 3: 128-wide exclusive scan of hist via shuffles (replaces 98-step serial scan)
    if (t >= 192) {
        int l = t - 192;
        unsigned origA = (l < K) ? hist[l] : 0u;
        unsigned origB = (l + 64 < K) ? hist[l + 64] : 0u;
        unsigned a = origA, b = origB;
        #pragma unroll
        for (int off = 1; off < 64; off <<= 1) {
            unsigned va = __shfl_up(a, off, 64);
            unsigned vb = __shfl_up(b, off, 64);
            if (l >= off) { a += va; b += vb; }
        }
        unsigned totA = __shfl(a, 63, 64);
        unsigned grand = totA + __shfl(b, 63, 64);
        scanv[l] = a - origA;                 // exclusive prefix, first half
        scanv[l + 64] = totA + b - origB;     // exclusive prefix, second half
        if (l == 63) scanv[K] = grand;        // consistent with regular write at K (inputs>=K are 0)
    }
    __syncthreads();   // B2: scan done (atomic returns drain here, overlapped with scan)
    if (t < (unsigned)K) gstart[t] = res;
    for (int k = t; k < K; k += TPB1) hist[k] = scanv[k];  // running cursors
    __syncthreads();   // B3
    // phase-2 scatter into stage (rank atomic)
    #pragma unroll
    for (int i = 0; i < PERT; i++) {
        if (bk[i] != 0xFFFFFFFFu) {
            unsigned slot = atomicAdd(&hist[bk[i]], 1u);
            stage[slot] = rc[i];
            bucket_of[slot] = (unsigned char)bk[i];
        }
    }
    __syncthreads();   // B4
    // coalesced write-out into (bucket,sub) regions
    unsigned total = scanv[K];
    for (unsigned j = t; j < total; j += TPB1) {
        unsigned b_ = bucket_of[j];
        unsigned off = gstart[b_] + (j - scanv[b_]);
        if (off < csub) recs[(size_t)(b_ * NSUB + sub) * csub + off] = stage[j];
        else            rec_to_acc4(stage[j], b_, acc4);   // statistical impossibility; safe anyway
    }
}

// u64-packed LDS accumulate: 2 LDS atomics/record instead of 4.
// accA = (mx_b << 32) | my_b ; accB = (mz_b << 32) | count, fields biased by 2^22
// per record so they stay non-negative (no carry across the 32-bit boundary:
// worst per-(node,slice) sum ~ 110 recs * 2^23 ~ 2^30 << 2^32).
__device__ __forceinline__ void proc_rec2(uint2 rv,
                                          unsigned long long* accA,
                                          unsigned long long* accB) {
    unsigned long long u = ((unsigned long long)rv.y << 32) | rv.x;
    unsigned lid = (unsigned)(u & (RANGE - 1));
    float mx = __half2float(__ushort_as_half((unsigned short)((u >> 11) & 0xFFFF)));
    float my = __half2float(__ushort_as_half((unsigned short)((u >> 27) & 0xFFFF)));
    float mz = __half2float(__ushort_as_half((unsigned short)((u >> 43) & 0xFFFF)));
    unsigned ix = (unsigned)(__float2int_rn(mx * FS2) + FBIAS);
    unsigned iy = (unsigned)(__float2int_rn(my * FS2) + FBIAS);
    unsigned iz = (unsigned)(__float2int_rn(mz * FS2) + FBIAS);
    atomicAdd(&accA[lid], ((unsigned long long)ix << 32) | (unsigned long long)iy);
    atomicAdd(&accB[lid], ((unsigned long long)iz << 32) | 1ull);
}

// region reduce -> coalesced slice stores (NO global atomics: R1 showed they cost ~40us)
__global__ __launch_bounds__(256) void reduce4_kernel(
        const uint2* __restrict__ recs, const unsigned* __restrict__ cursor,
        uint4* __restrict__ slices, int N, int K, unsigned csub) {
    __shared__ unsigned long long accA[RANGE];   // 8 KB
    __shared__ unsigned long long accB[RANGE];   // 8 KB
    const int b = blockIdx.x / NSLICE;
    const int s = blockIdx.x % NSLICE;
    const int r = s & (NSUB - 1);      // sub-region
    const int p = s / NSUB;            // half of the sub-region
    for (int i = threadIdx.x; i < RANGE; i += 256) { accA[i] = 0ull; accB[i] = 0ull; }
    __syncthreads();
    unsigned cnt = cursor[b * NSUB + r];
    if (cnt > csub) cnt = csub;        // overflow recs went straight to acc4
    unsigned per = (cnt + 1) >> 1;
    unsigned st = (unsigned)p * per;
    unsigned en = st + per; if (en > cnt) en = cnt;
    const uint2* rb = recs + (size_t)(b * NSUB + r) * csub;
    unsigned j = st + threadIdx.x;
    if (st < cnt) {
        while (j + 256 < en) {
            uint2 r0 = rb[j];
            uint2 r1 = rb[j + 256];
            proc_rec2(r0, accA, accB);
            proc_rec2(r1, accA, accB);
            j += 512;
        }
        while (j < en) { proc_rec2(rb[j], accA, accB); j += 256; }
    }
    __syncthreads();
    const int nbase = b * RANGE;
    for (int i = threadIdx.x; i < RANGE; i += 256) {
        int node = nbase + i;
        if (node < N) {
            unsigned long long A = accA[i], B = accB[i];
            slices[(size_t)s * N + node] =
                make_uint4((unsigned)(A >> 32), (unsigned)A,
                           (unsigned)(B >> 32), (unsigned)B);
        }
    }
}

// final node pass: merge biased slice sums + (rare) overflow acc4, fuse velocity MLP
__global__ void node_merge_kernel(const float* __restrict__ x,
                                  const float* __restrict__ vel_norm,
                                  const float* __restrict__ vel,
                                  const float* __restrict__ W1, const float* __restrict__ b1,
                                  const float* __restrict__ W2, const float* __restrict__ b2,
                                  const uint4* __restrict__ slices,
                                  const uint4* __restrict__ acc4,
                                  float* __restrict__ out, int N) {
    __shared__ float sW1[HDIM], sb1[HDIM], sW2[HDIM];
    for (int k = threadIdx.x; k < HDIM; k += blockDim.x) {
        sW1[k] = W1[k]; sb1[k] = b1[k]; sW2[k] = W2[k];
    }
    __syncthreads();
    int i = blockIdx.x * blockDim.x + threadIdx.x;
    if (i >= N) return;
    unsigned long long sxb = 0, syb = 0, szb = 0;
    unsigned sc = 0;
    #pragma unroll
    for (int s = 0; s < NSLICE; s++) {
        uint4 v = slices[(size_t)s * N + i];
        sxb += v.x; syb += v.y; szb += v.z; sc += v.w;
    }
    uint4 a4 = acc4[i];  // overflow contribution (normally zero)
    long long fx = (long long)sxb - (long long)sc * (long long)FBIAS + (long long)(int)a4.x;
    long long fy = (long long)syb - (long long)sc * (long long)FBIAS + (long long)(int)a4.y;
    long long fz = (long long)szb - (long long)sc * (long long)FBIAS + (long long)(int)a4.z;
    float cntf = (float)(sc + a4.w);
    float sx = (float)fx * INVFS2;
    float sy = (float)fy * INVFS2;
    float sz = (float)fz * INVFS2;
    float vn = vel_norm[i];
    float a = b2[0];
    #pragma unroll
    for (int k = 0; k < HDIM; k++) {
        float h = fmaf(vn, sW1[k], sb1[k]);
        h = (h > 0.f) ? h : LEAKY * h;
        a = fmaf(sW2[k], h, a);
    }
    float inv = 1.0f / fmaxf(cntf, 1.0f);
    out[3*i]     = x[3*i]     + sx * inv + vel[3*i]     * a;
    out[3*i + 1] = x[3*i + 1] + sy * inv + vel[3*i + 1] * a;
    out[3*i + 2] = x[3*i + 2] + sz * inv + vel[3*i + 2] * a;
}

// ---- plain-atomic fallback path (K > KMAX or tiny workspace) ----
__global__ void precompute_kernel(const float* __restrict__ Wp1,
                                  const float* __restrict__ bp1,
                                  const float* __restrict__ Wp2,
                                  float* __restrict__ consts) {
    int k = threadIdx.x;
    float w1 = Wp1[k];
    float slope = (w1 >= 0.f) ? 1.f : LEAKY;
    float c = Wp2[k] * w1 * slope;
    float bnz = (bp1[k] != 0.f) ? 1.f : 0.f;
    #pragma unroll
    for (int off = 32; off > 0; off >>= 1) {
        c += __shfl_down(c, off, 64);
        bnz += __shfl_down(bnz, off, 64);
    }
    if (k == 0) { consts[0] = c; consts[1] = bnz; }
}

__global__ void edge_atomic_kernel(const float* __restrict__ x, const int* __restrict__ ei,
                                   const float* __restrict__ Wp1, const float* __restrict__ bp1,
                                   const float* __restrict__ Wp2, const float* __restrict__ consts,
                                   float* __restrict__ acc, int E) {
    __shared__ float sW1[HDIM], sb1[HDIM], sW2[HDIM];
    const float C = consts[0];
    const bool slow = (consts[1] != 0.f);
    if (slow) {
        for (int k = threadIdx.x; k < HDIM; k += blockDim.x) {
            sW1[k] = Wp1[k]; sb1[k] = bp1[k]; sW2[k] = Wp2[k];
        }
        __syncthreads();
    }
    int e = blockIdx.x * blockDim.x + threadIdx.x;
    if (e >= E) return;
    int r = ei[e];
    int c = ei[E + e];
    float dx = x[3*r] - x[3*c];
    float dy = x[3*r+1] - x[3*c+1];
    float dz = x[3*r+2] - x[3*c+2];
    float rad = sqrtf(dx*dx + dy*dy + dz*dz);
    float eo = edge_eo(rad, C, slow, sW1, sb1, sW2);
    float* basep = acc + ((size_t)r << 2);
    atomicAdd(basep + 0, dx * eo);
    atomicAdd(basep + 1, dy * eo);
    atomicAdd(basep + 2, dz * eo);
    atomicAdd(basep + 3, 1.f);
}

__global__ void node_kernel(const float* __restrict__ x, const float* __restrict__ vel_norm,
                            const float* __restrict__ vel,
                            const float* __restrict__ W1, const float* __restrict__ b1,
                            const float* __restrict__ W2, const float* __restrict__ b2,
                            const float4* __restrict__ slices,
                            float* __restrict__ out, int N, int S) {
    __shared__ float sW1[HDIM], sb1[HDIM], sW2[HDIM];
    for (int k = threadIdx.x; k < HDIM; k += blockDim.x) {
        sW1[k] = W1[k]; sb1[k] = b1[k]; sW2[k] = W2[k];
    }
    __syncthreads();
    int i = blockIdx.x * blockDim.x + threadIdx.x;
    if (i >= N) return;
    float sx = 0.f, sy = 0.f, sz = 0.f, sc = 0.f;
    for (int s = 0; s < S; s++) {
        float4 v = slices[(size_t)s * N + i];
        sx += v.x; sy += v.y; sz += v.z; sc += v.w;
    }
    float vn = vel_norm[i];
    float a = b2[0];
    #pragma unroll
    for (int k = 0; k < HDIM; k++) {
        float h = fmaf(vn, sW1[k], sb1[k]);
        h = (h > 0.f) ? h : LEAKY * h;
        a = fmaf(sW2[k], h, a);
    }
    float inv = 1.0f / fmaxf(sc, 1.0f);
    out[3*i]     = x[3*i]     + sx * inv + vel[3*i]     * a;
    out[3*i + 1] = x[3*i + 1] + sy * inv + vel[3*i + 1] * a;
    out[3*i + 2] = x[3*i + 2] + sz * inv + vel[3*i + 2] * a;
}

extern "C" void kernel_launch(void* const* d_in, const int* in_sizes, int n_in,
                              void* d_out, int out_size, void* d_ws, size_t ws_size,
                              hipStream_t stream) {
    const float* x        = (const float*)d_in[0];
    const float* vel_norm = (const float*)d_in[1];
    const float* vel      = (const float*)d_in[2];
    const int*   ei       = (const int*)  d_in[3];
    const float* W1       = (const float*)d_in[4];
    const float* b1       = (const float*)d_in[5];
    const float* W2       = (const float*)d_in[6];
    const float* b2       = (const float*)d_in[7];
    const float* Wp1      = (const float*)d_in[8];
    const float* bp1      = (const float*)d_in[9];
    const float* Wp2      = (const float*)d_in[10];

    const int N = in_sizes[0] / 3;
    const int E = in_sizes[3] / 2;
    const int K = (N + RANGE - 1) / RANGE;
    const int nblk = (E + EPB - 1) / EPB;

    // per-(bucket,sub) capacity: mean + 1024 (~8 sigma); overflow -> direct atomics
    unsigned csub = (unsigned)(E / (K * NSUB)) + 1024u;
    csub = (csub + 63u) & ~63u;

    // layout: [recs: K*NSUB*csub*8] [slices: NSLICE*N*16] [xh: N*8] [acc4: N*16] [cursor] [consts]
    size_t rec_bytes = (size_t)K * NSUB * csub * sizeof(uint2);
    size_t sp_slices = rec_bytes;
    size_t sp_xh     = sp_slices + (size_t)NSLICE * N * sizeof(uint4);
    size_t sp_acc    = (sp_xh + (size_t)N * sizeof(uint2) + 15) & ~(size_t)15;
    size_t sp_cur    = sp_acc + (size_t)N * sizeof(uint4);
    size_t sp_const  = (sp_cur + (size_t)NSUB * KMAX * sizeof(unsigned) + 15) & ~(size_t)15;
    size_t need      = sp_const + 32;

    if (K <= KMAX && ws_size >= need) {
        uint2*    recs   = (uint2*)   d_ws;
        uint4*    slices = (uint4*)   ((char*)d_ws + sp_slices);
        uint2*    xh     = (uint2*)   ((char*)d_ws + sp_xh);
        unsigned* acc4   = (unsigned*)((char*)d_ws + sp_acc);
        unsigned* cursor = (unsigned*)((char*)d_ws + sp_cur);
        float*    consts = (float*)   ((char*)d_ws + sp_const);

        repack_h_kernel<<<(N + 255) / 256, 256, 0, stream>>>(
            x, xh, N, Wp1, bp1, Wp2, consts, (uint4*)acc4, cursor, K);
        fused4_kernel<<<nblk, TPB1, 0, stream>>>(
            xh, ei, Wp1, bp1, Wp2, consts, cursor, acc4, recs, E, K, csub);
        reduce4_kernel<<<K * NSLICE, 256, 0, stream>>>(recs, cursor, slices, N, K, csub);
        node_merge_kernel<<<(N + 255) / 256, 256, 0, stream>>>(
            x, vel_norm, vel, W1, b1, W2, b2, slices, (const uint4*)acc4,
            (float*)d_out, N);
    } else {
        float* acc    = (float*)d_ws;
        float* consts = (float*)((char*)d_ws + (size_t)N * sizeof(float4));
        hipMemsetAsync(d_ws, 0, (size_t)N * sizeof(float4) + 32, stream);
        precompute_kernel<<<1, 64, 0, stream>>>(Wp1, bp1, Wp2, consts);
        edge_atomic_kernel<<<(E + 255) / 256, 256, 0, stream>>>(x, ei, Wp1, bp1, Wp2,
                                                                consts, acc, E);
        node_kernel<<<(N + 255) / 256, 256, 0, stream>>>(x, vel_norm, vel, W1, b1, W2, b2,
                                                         (const float4*)acc, (float*)d_out, N, 1);
    }
}

// Round 3
// 185.805 us; speedup vs baseline: 1.2761x; 1.0194x over previous
//
#include <hip/hip_runtime.h>
#include <hip/hip_fp16.h>
#include <math.h>

#define LEAKY 0.2f
#define HDIM 64
#define EPB 4096            // edges per block (fused) — R3: doubled to amortize scan/barriers
#define TPB1 256
#define PERT (EPB / TPB1)   // 16 edges per thread (two half-batches of 8)
#define RANGE 1024          // nodes per bucket
#define RSH 10
#define KMAX 128
#define NSUB 4              // sub-cursors per bucket (contention mitigation)
#define NSLICE 8            // reduce slices per bucket = NSUB * 2
#define FS2 262144.0f       // 2^18 fixed-point scale
#define INVFS2 (1.0f / 262144.0f)
#define FBIAS 4194304       // 2^22 per-record field bias (keeps packed u32 fields non-negative)

// record: bits [0,11) lid, [11,27) f16 mx, [27,43) f16 my, [43,59) f16 mz

// tanh(v) = 1 - 2/(exp2(v*2*log2e)+1); exact saturation, ~1e-6 rel err (R10/11-verified)
__device__ __forceinline__ float fast_tanh(float v) {
    float e = __builtin_amdgcn_exp2f(v * 2.88539008178f);
    return 1.0f - 2.0f * __builtin_amdgcn_rcpf(e + 1.0f);
}

__device__ __forceinline__ float edge_eo(float rad, float C, bool slow,
                                         const float* sW1, const float* sb1,
                                         const float* sW2) {
    if (!slow) return fast_tanh(C * rad);  // bp1==0, rad>=0: MLP collapses to linear
    float a = 0.f;
    #pragma unroll
    for (int k = 0; k < HDIM; k++) {
        float h = fmaf(rad, sW1[k], sb1[k]);
        h = (h > 0.f) ? h : LEAKY * h;
        a = fmaf(sW2[k], h, a);
    }
    return fast_tanh(a);
}

// half-packed coords + consts precompute + acc4/cursor zero-init (one dispatch)
__global__ void repack_h_kernel(const float* __restrict__ x, uint2* __restrict__ xh, int N,
                                const float* __restrict__ Wp1, const float* __restrict__ bp1,
                                const float* __restrict__ Wp2, float* __restrict__ consts,
                                uint4* __restrict__ acc4, unsigned* __restrict__ cursor, int K) {
    int i = blockIdx.x * blockDim.x + threadIdx.x;
    if (i < N) {
        unsigned hx = __half_as_ushort(__float2half(x[3*i]));
        unsigned hy = __half_as_ushort(__float2half(x[3*i+1]));
        unsigned hz = __half_as_ushort(__float2half(x[3*i+2]));
        xh[i] = make_uint2((hy << 16) | hx, hz);
        acc4[i] = make_uint4(0u, 0u, 0u, 0u);
    }
    if (blockIdx.x == 0) {
        if (threadIdx.x < 64) {
            int k = threadIdx.x;   // one wave: shuffle reduction valid
            float w1 = Wp1[k];
            float slope = (w1 >= 0.f) ? 1.f : LEAKY;
            float c = Wp2[k] * w1 * slope;
            float bnz = (bp1[k] != 0.f) ? 1.f : 0.f;
            #pragma unroll
            for (int off = 32; off > 0; off >>= 1) {
                c += __shfl_down(c, off, 64);
                bnz += __shfl_down(bnz, off, 64);
            }
            if (k == 0) { consts[0] = c; consts[1] = bnz; }
        }
        for (int k = threadIdx.x; k < NSUB * K; k += 256) cursor[k] = 0u;
    }
}

__device__ __forceinline__ unsigned long long pack_rec(float dx, float dy, float dz,
                                                       float eo, unsigned lid) {
    unsigned hx = __half_as_ushort(__float2half(dx * eo));
    unsigned hy = __half_as_ushort(__float2half(dy * eo));
    unsigned hz = __half_as_ushort(__float2half(dz * eo));
    return (unsigned long long)lid
         | ((unsigned long long)hx << 11)
         | ((unsigned long long)hy << 27)
         | ((unsigned long long)hz << 43);
}

__device__ __forceinline__ uint2 make_record(uint2 ga, uint2 gb, int r,
                                             float C, bool slow,
                                             const float* sW1, const float* sb1,
                                             const float* sW2) {
    float ax = __half2float(__ushort_as_half((unsigned short)(ga.x & 0xFFFF)));
    float ay = __half2float(__ushort_as_half((unsigned short)(ga.x >> 16)));
    float az = __half2float(__ushort_as_half((unsigned short)(ga.y & 0xFFFF)));
    float bx = __half2float(__ushort_as_half((unsigned short)(gb.x & 0xFFFF)));
    float by = __half2float(__ushort_as_half((unsigned short)(gb.x >> 16)));
    float bz = __half2float(__ushort_as_half((unsigned short)(gb.y & 0xFFFF)));
    float dx = ax - bx, dy = ay - by, dz = az - bz;
    float rad = sqrtf(dx*dx + dy*dy + dz*dz);
    float eo = edge_eo(rad, C, slow, sW1, sb1, sW2);
    unsigned long long u = pack_rec(dx, dy, dz, eo, (unsigned)r & (RANGE - 1));
    return make_uint2((unsigned)u, (unsigned)(u >> 32));
}

// direct fixed-point global-atomic fallback for a packed record (bucket overflow only;
// unbiased signed 2^18 fixed — two's-complement wrap makes separate u32 adds exact)
__device__ __forceinline__ void rec_to_acc4(uint2 r, unsigned b_, unsigned* acc4) {
    unsigned long long u = ((unsigned long long)r.y << 32) | r.x;
    unsigned lid = (unsigned)(u & (RANGE - 1));
    unsigned node = b_ * RANGE + lid;
    float mx = __half2float(__ushort_as_half((unsigned short)((u >> 11) & 0xFFFF)));
    float my = __half2float(__ushort_as_half((unsigned short)((u >> 27) & 0xFFFF)));
    float mz = __half2float(__ushort_as_half((unsigned short)((u >> 43) & 0xFFFF)));
    atomicAdd(&acc4[4*node + 0], (unsigned)__float2int_rn(mx * FS2));
    atomicAdd(&acc4[4*node + 1], (unsigned)__float2int_rn(my * FS2));
    atomicAdd(&acc4[4*node + 2], (unsigned)__float2int_rn(mz * FS2));
    atomicAdd(&acc4[4*node + 3], 1u);
}

// ---- FUSED compute+sort, R3 structure:
//  - EPB=4096 (two half-batches of 8 records: caps VGPR while keeping 16 gathers/half)
//  - wave-3 shuffle scan writes scanv AND cur (separate cursor array) -> one less barrier
//  - cursor reservation issued after B1; its return consumed AFTER the scatter phase
__global__ __launch_bounds__(TPB1) void fused5_kernel(
        const uint2* __restrict__ xh,
        const int* __restrict__ ei,
        const float* __restrict__ Wp1, const float* __restrict__ bp1,
        const float* __restrict__ Wp2, const float* __restrict__ consts,
        unsigned* __restrict__ cursor, unsigned* __restrict__ acc4,
        uint2* __restrict__ recs, int E, int K, unsigned csub) {
    __shared__ uint2 stage[EPB];                 // 32 KB
    __shared__ unsigned char bucket_of[EPB];     // 4 KB
    __shared__ unsigned hist[KMAX];
    __shared__ unsigned scanv[KMAX + 1];
    __shared__ unsigned cur[KMAX];
    __shared__ unsigned gstart[KMAX];
    __shared__ float sW1[HDIM], sb1[HDIM], sW2[HDIM];
    const float C = consts[0];
    const bool slow = (consts[1] != 0.f);
    const unsigned sub = (unsigned)blockIdx.x & (NSUB - 1);
    if (slow) {
        for (int k = threadIdx.x; k < HDIM; k += TPB1) {
            sW1[k] = Wp1[k]; sb1[k] = bp1[k]; sW2[k] = Wp2[k];
        }
    }
    for (int k = threadIdx.x; k < K; k += TPB1) hist[k] = 0;
    __syncthreads();   // B0

    const size_t base = (size_t)blockIdx.x * EPB;
    const unsigned t = threadIdx.x;
    uint2 rc[PERT];
    unsigned bk[PERT];
    if (base + EPB <= (size_t)E && (E & 3) == 0) {
        const int4* pr = (const int4*)(ei + base);
        const int4* pc = (const int4*)(ei + (size_t)E + base);
        // all index quads up front (coalesced)
        int4 rv0 = pr[t];
        int4 rv1 = pr[t + TPB1];
        int4 rv2 = pr[t + 2 * TPB1];
        int4 rv3 = pr[t + 3 * TPB1];
        int4 cv0 = pc[t];
        int4 cv1 = pc[t + TPB1];
        int4 cv2 = pc[t + 2 * TPB1];
        int4 cv3 = pc[t + 3 * TPB1];
        // half 0: 16 gathers in flight before first use
        {
            uint2 ga0 = xh[rv0.x], ga1 = xh[rv0.y], ga2 = xh[rv0.z], ga3 = xh[rv0.w];
            uint2 ga4 = xh[rv1.x], ga5 = xh[rv1.y], ga6 = xh[rv1.z], ga7 = xh[rv1.w];
            uint2 gb0 = xh[cv0.x], gb1 = xh[cv0.y], gb2 = xh[cv0.z], gb3 = xh[cv0.w];
            uint2 gb4 = xh[cv1.x], gb5 = xh[cv1.y], gb6 = xh[cv1.z], gb7 = xh[cv1.w];
            rc[0] = make_record(ga0, gb0, rv0.x, C, slow, sW1, sb1, sW2);
            rc[1] = make_record(ga1, gb1, rv0.y, C, slow, sW1, sb1, sW2);
            rc[2] = make_record(ga2, gb2, rv0.z, C, slow, sW1, sb1, sW2);
            rc[3] = make_record(ga3, gb3, rv0.w, C, slow, sW1, sb1, sW2);
            rc[4] = make_record(ga4, gb4, rv1.x, C, slow, sW1, sb1, sW2);
            rc[5] = make_record(ga5, gb5, rv1.y, C, slow, sW1, sb1, sW2);
            rc[6] = make_record(ga6, gb6, rv1.z, C, slow, sW1, sb1, sW2);
            rc[7] = make_record(ga7, gb7, rv1.w, C, slow, sW1, sb1, sW2);
        }
        // half 1
        {
            uint2 ga0 = xh[rv2.x], ga1 = xh[rv2.y], ga2 = xh[rv2.z], ga3 = xh[rv2.w];
            uint2 ga4 = xh[rv3.x], ga5 = xh[rv3.y], ga6 = xh[rv3.z], ga7 = xh[rv3.w];
            uint2 gb0 = xh[cv2.x], gb1 = xh[cv2.y], gb2 = xh[cv2.z], gb3 = xh[cv2.w];
            uint2 gb4 = xh[cv3.x], gb5 = xh[cv3.y], gb6 = xh[cv3.z], gb7 = xh[cv3.w];
            rc[8]  = make_record(ga0, gb0, rv2.x, C, slow, sW1, sb1, sW2);
            rc[9]  = make_record(ga1, gb1, rv2.y, C, slow, sW1, sb1, sW2);
            rc[10] = make_record(ga2, gb2, rv2.z, C, slow, sW1, sb1, sW2);
            rc[11] = make_record(ga3, gb3, rv2.w, C, slow, sW1, sb1, sW2);
            rc[12] = make_record(ga4, gb4, rv3.x, C, slow, sW1, sb1, sW2);
            rc[13] = make_record(ga5, gb5, rv3.y, C, slow, sW1, sb1, sW2);
            rc[14] = make_record(ga6, gb6, rv3.z, C, slow, sW1, sb1, sW2);
            rc[15] = make_record(ga7, gb7, rv3.w, C, slow, sW1, sb1, sW2);
        }
        bk[0]  = (unsigned)rv0.x >> RSH; bk[1]  = (unsigned)rv0.y >> RSH;
        bk[2]  = (unsigned)rv0.z >> RSH; bk[3]  = (unsigned)rv0.w >> RSH;
        bk[4]  = (unsigned)rv1.x >> RSH; bk[5]  = (unsigned)rv1.y >> RSH;
        bk[6]  = (unsigned)rv1.z >> RSH; bk[7]  = (unsigned)rv1.w >> RSH;
        bk[8]  = (unsigned)rv2.x >> RSH; bk[9]  = (unsigned)rv2.y >> RSH;
        bk[10] = (unsigned)rv2.z >> RSH; bk[11] = (unsigned)rv2.w >> RSH;
        bk[12] = (unsigned)rv3.x >> RSH; bk[13] = (unsigned)rv3.y >> RSH;
        bk[14] = (unsigned)rv3.z >> RSH; bk[15] = (unsigned)rv3.w >> RSH;
        #pragma unroll
        for (int i = 0; i < PERT; i++) atomicAdd(&hist[bk[i]], 1u);
    } else {
        #pragma unroll
        for (int i = 0; i < PERT; i++) {
            size_t e = base + (size_t)i * TPB1 + t;
            bk[i] = 0xFFFFFFFFu;
            if (e < (size_t)E) {
                int r = ei[e];
                int c = ei[(size_t)E + e];
                uint2 ga = xh[r], gb = xh[c];
                rc[i] = make_record(ga, gb, r, C, slow, sW1, sb1, sW2);
                bk[i] = (unsigned)r >> RSH;
                atomicAdd(&hist[bk[i]], 1u);
            }
        }
    }
    __syncthreads();   // B1: hist complete
    // issue reservation immediately (waves 0-1); return consumed only after scatter
    unsigned res = 0;
    if (t < (unsigned)K) {
        unsigned myc = hist[t];
        if (myc) res = atomicAdd(&cursor[t * NSUB + sub], myc);
    }
    // wave 3: 128-wide exclusive scan of hist via shuffles; writes BOTH scanv and cur
    if (t >= 192) {
        int l = t - 192;
        unsigned origA = (l < K) ? hist[l] : 0u;
        unsigned origB = (l + 64 < K) ? hist[l + 64] : 0u;
        unsigned a = origA, b = origB;
        #pragma unroll
        for (int off = 1; off < 64; off <<= 1) {
            unsigned va = __shfl_up(a, off, 64);
            unsigned vb = __shfl_up(b, off, 64);
            if (l >= off) { a += va; b += vb; }
        }
        unsigned totA = __shfl(a, 63, 64);
        unsigned grand = totA + __shfl(b, 63, 64);
        unsigned exA = a - origA;
        unsigned exB = totA + b - origB;
        scanv[l] = exA;  cur[l] = exA;
        scanv[l + 64] = exB;  cur[l + 64] = exB;
        if (l == 63) scanv[K] = grand;   // K<=128; slots >=K got 0-count prefixes (harmless)
    }
    __syncthreads();   // B2: scanv + cur ready
    // phase-2 scatter into stage (rank atomic on cur)
    #pragma unroll
    for (int i = 0; i < PERT; i++) {
        if (bk[i] != 0xFFFFFFFFu) {
            unsigned slot = atomicAdd(&cur[bk[i]], 1u);
            stage[slot] = rc[i];
            bucket_of[slot] = (unsigned char)bk[i];
        }
    }
    if (t < (unsigned)K) gstart[t] = res;   // atomic-return wait lands here, after scatter
    __syncthreads();   // B3
    // coalesced write-out into (bucket,sub) regions
    unsigned total = scanv[K];
    for (unsigned j = t; j < total; j += TPB1) {
        unsigned b_ = bucket_of[j];
        unsigned off = gstart[b_] + (j - scanv[b_]);
        if (off < csub) recs[(size_t)(b_ * NSUB + sub) * csub + off] = stage[j];
        else            rec_to_acc4(stage[j], b_, acc4);   // statistical impossibility; safe anyway
    }
}

// u64-packed LDS accumulate: 2 LDS atomics/record instead of 4.
// accA = (mx_b << 32) | my_b ; accB = (mz_b << 32) | count, fields biased by 2^22
// per record so they stay non-negative (no carry across the 32-bit boundary:
// worst per-(node,slice) sum ~ 110 recs * 2^23 ~ 2^30 << 2^32).
__device__ __forceinline__ void proc_rec2(unsigned lo, unsigned hi,
                                          unsigned long long* accA,
                                          unsigned long long* accB) {
    unsigned long long u = ((unsigned long long)hi << 32) | lo;
    unsigned lid = (unsigned)(u & (RANGE - 1));
    float mx = __half2float(__ushort_as_half((unsigned short)((u >> 11) & 0xFFFF)));
    float my = __half2float(__ushort_as_half((unsigned short)((u >> 27) & 0xFFFF)));
    float mz = __half2float(__ushort_as_half((unsigned short)((u >> 43) & 0xFFFF)));
    unsigned ix = (unsigned)(__float2int_rn(mx * FS2) + FBIAS);
    unsigned iy = (unsigned)(__float2int_rn(my * FS2) + FBIAS);
    unsigned iz = (unsigned)(__float2int_rn(mz * FS2) + FBIAS);
    atomicAdd(&accA[lid], ((unsigned long long)ix << 32) | (unsigned long long)iy);
    atomicAdd(&accB[lid], ((unsigned long long)iz << 32) | 1ull);
}

// region reduce -> coalesced slice stores. R3: uint4 loads (2 records each) + unroll-2
// -> 4 records / 32B in flight per thread per iteration.
__global__ __launch_bounds__(256) void reduce5_kernel(
        const uint2* __restrict__ recs, const unsigned* __restrict__ cursor,
        uint4* __restrict__ slices, int N, int K, unsigned csub) {
    __shared__ unsigned long long accA[RANGE];   // 8 KB
    __shared__ unsigned long long accB[RANGE];   // 8 KB
    const int b = blockIdx.x / NSLICE;
    const int s = blockIdx.x % NSLICE;
    const int r = s & (NSUB - 1);      // sub-region
    const int p = s / NSUB;            // half of the sub-region
    for (int i = threadIdx.x; i < RANGE; i += 256) { accA[i] = 0ull; accB[i] = 0ull; }
    __syncthreads();
    unsigned cnt = cursor[b * NSUB + r];
    if (cnt > csub) cnt = csub;        // overflow recs went straight to acc4
    unsigned pairs = (cnt + 1) >> 1;
    unsigned perp = (pairs + 1) >> 1;
    unsigned p0 = (unsigned)p * perp;
    unsigned p1 = p0 + perp; if (p1 > pairs) p1 = pairs;
    const uint4* rb4 = (const uint4*)(recs + (size_t)(b * NSUB + r) * csub);
    unsigned j = p0 + threadIdx.x;
    if (p0 < p1) {
        while (j + 256 < p1) {
            uint4 v0 = rb4[j];
            uint4 v1 = rb4[j + 256];
            proc_rec2(v0.x, v0.y, accA, accB);
            if (2*j + 1 < cnt) proc_rec2(v0.z, v0.w, accA, accB);
            proc_rec2(v1.x, v1.y, accA, accB);
            if (2*(j+256) + 1 < cnt) proc_rec2(v1.z, v1.w, accA, accB);
            j += 512;
        }
        while (j < p1) {
            uint4 v = rb4[j];
            proc_rec2(v.x, v.y, accA, accB);
            if (2*j + 1 < cnt) proc_rec2(v.z, v.w, accA, accB);
            j += 256;
        }
    }
    __syncthreads();
    const int nbase = b * RANGE;
    for (int i = threadIdx.x; i < RANGE; i += 256) {
        int node = nbase + i;
        if (node < N) {
            unsigned long long A = accA[i], B = accB[i];
            slices[(size_t)s * N + node] =
                make_uint4((unsigned)(A >> 32), (unsigned)A,
                           (unsigned)(B >> 32), (unsigned)B);
        }
    }
}

// final node pass: merge biased slice sums + (rare) overflow acc4, fuse velocity MLP
__global__ void node_merge_kernel(const float* __restrict__ x,
                                  const float* __restrict__ vel_norm,
                                  const float* __restrict__ vel,
                                  const float* __restrict__ W1, const float* __restrict__ b1,
                                  const float* __restrict__ W2, const float* __restrict__ b2,
                                  const uint4* __restrict__ slices,
                                  const uint4* __restrict__ acc4,
                                  float* __restrict__ out, int N) {
    __shared__ float sW1[HDIM], sb1[HDIM], sW2[HDIM];
    for (int k = threadIdx.x; k < HDIM; k += blockDim.x) {
        sW1[k] = W1[k]; sb1[k] = b1[k]; sW2[k] = W2[k];
    }
    __syncthreads();
    int i = blockIdx.x * blockDim.x + threadIdx.x;
    if (i >= N) return;
    unsigned long long sxb = 0, syb = 0, szb = 0;
    unsigned sc = 0;
    #pragma unroll
    for (int s = 0; s < NSLICE; s++) {
        uint4 v = slices[(size_t)s * N + i];
        sxb += v.x; syb += v.y; szb += v.z; sc += v.w;
    }
    uint4 a4 = acc4[i];  // overflow contribution (normally zero)
    long long fx = (long long)sxb - (long long)sc * (long long)FBIAS + (long long)(int)a4.x;
    long long fy = (long long)syb - (long long)sc * (long long)FBIAS + (long long)(int)a4.y;
    long long fz = (long long)szb - (long long)sc * (long long)FBIAS + (long long)(int)a4.z;
    float cntf = (float)(sc + a4.w);
    float sx = (float)fx * INVFS2;
    float sy = (float)fy * INVFS2;
    float sz = (float)fz * INVFS2;
    float vn = vel_norm[i];
    float a = b2[0];
    #pragma unroll
    for (int k = 0; k < HDIM; k++) {
        float h = fmaf(vn, sW1[k], sb1[k]);
        h = (h > 0.f) ? h : LEAKY * h;
        a = fmaf(sW2[k], h, a);
    }
    float inv = 1.0f / fmaxf(cntf, 1.0f);
    out[3*i]     = x[3*i]     + sx * inv + vel[3*i]     * a;
    out[3*i + 1] = x[3*i + 1] + sy * inv + vel[3*i + 1] * a;
    out[3*i + 2] = x[3*i + 2] + sz * inv + vel[3*i + 2] * a;
}

// ---- plain-atomic fallback path (K > KMAX or tiny workspace) ----
__global__ void precompute_kernel(const float* __restrict__ Wp1,
                                  const float* __restrict__ bp1,
                                  const float* __restrict__ Wp2,
                                  float* __restrict__ consts) {
    int k = threadIdx.x;
    float w1 = Wp1[k];
    float slope = (w1 >= 0.f) ? 1.f : LEAKY;
    float c = Wp2[k] * w1 * slope;
    float bnz = (bp1[k] != 0.f) ? 1.f : 0.f;
    #pragma unroll
    for (int off = 32; off > 0; off >>= 1) {
        c += __shfl_down(c, off, 64);
        bnz += __shfl_down(bnz, off, 64);
    }
    if (k == 0) { consts[0] = c; consts[1] = bnz; }
}

__global__ void edge_atomic_kernel(const float* __restrict__ x, const int* __restrict__ ei,
                                   const float* __restrict__ Wp1, const float* __restrict__ bp1,
                                   const float* __restrict__ Wp2, const float* __restrict__ consts,
                                   float* __restrict__ acc, int E) {
    __shared__ float sW1[HDIM], sb1[HDIM], sW2[HDIM];
    const float C = consts[0];
    const bool slow = (consts[1] != 0.f);
    if (slow) {
        for (int k = threadIdx.x; k < HDIM; k += blockDim.x) {
            sW1[k] = Wp1[k]; sb1[k] = bp1[k]; sW2[k] = Wp2[k];
        }
        __syncthreads();
    }
    int e = blockIdx.x * blockDim.x + threadIdx.x;
    if (e >= E) return;
    int r = ei[e];
    int c = ei[E + e];
    float dx = x[3*r] - x[3*c];
    float dy = x[3*r+1] - x[3*c+1];
    float dz = x[3*r+2] - x[3*c+2];
    float rad = sqrtf(dx*dx + dy*dy + dz*dz);
    float eo = edge_eo(rad, C, slow, sW1, sb1, sW2);
    float* basep = acc + ((size_t)r << 2);
    atomicAdd(basep + 0, dx * eo);
    atomicAdd(basep + 1, dy * eo);
    atomicAdd(basep + 2, dz * eo);
    atomicAdd(basep + 3, 1.f);
}

__global__ void node_kernel(const float* __restrict__ x, const float* __restrict__ vel_norm,
                            const float* __restrict__ vel,
                            const float* __restrict__ W1, const float* __restrict__ b1,
                            const float* __restrict__ W2, const float* __restrict__ b2,
                            const float4* __restrict__ slices,
                            float* __restrict__ out, int N, int S) {
    __shared__ float sW1[HDIM], sb1[HDIM], sW2[HDIM];
    for (int k = threadIdx.x; k < HDIM; k += blockDim.x) {
        sW1[k] = W1[k]; sb1[k] = b1[k]; sW2[k] = W2[k];
    }
    __syncthreads();
    int i = blockIdx.x * blockDim.x + threadIdx.x;
    if (i >= N) return;
    float sx = 0.f, sy = 0.f, sz = 0.f, sc = 0.f;
    for (int s = 0; s < S; s++) {
        float4 v = slices[(size_t)s * N + i];
        sx += v.x; sy += v.y; sz += v.z; sc += v.w;
    }
    float vn = vel_norm[i];
    float a = b2[0];
    #pragma unroll
    for (int k = 0; k < HDIM; k++) {
        float h = fmaf(vn, sW1[k], sb1[k]);
        h = (h > 0.f) ? h : LEAKY * h;
        a = fmaf(sW2[k], h, a);
    }
    float inv = 1.0f / fmaxf(sc, 1.0f);
    out[3*i]     = x[3*i]     + sx * inv + vel[3*i]     * a;
    out[3*i + 1] = x[3*i + 1] + sy * inv + vel[3*i + 1] * a;
    out[3*i + 2] = x[3*i + 2] + sz * inv + vel[3*i + 2] * a;
}

extern "C" void kernel_launch(void* const* d_in, const int* in_sizes, int n_in,
                              void* d_out, int out_size, void* d_ws, size_t ws_size,
                              hipStream_t stream) {
    const float* x        = (const float*)d_in[0];
    const float* vel_norm = (const float*)d_in[1];
    const float* vel      = (const float*)d_in[2];
    const int*   ei       = (const int*)  d_in[3];
    const float* W1       = (const float*)d_in[4];
    const float* b1       = (const float*)d_in[5];
    const float* W2       = (const float*)d_in[6];
    const float* b2       = (const float*)d_in[7];
    const float* Wp1      = (const float*)d_in[8];
    const float* bp1      = (const float*)d_in[9];
    const float* Wp2      = (const float*)d_in[10];

    const int N = in_sizes[0] / 3;
    const int E = in_sizes[3] / 2;
    const int K = (N + RANGE - 1) / RANGE;
    const int nblk = (E + EPB - 1) / EPB;

    // per-(bucket,sub) capacity: mean + 1024 (~8 sigma); overflow -> direct atomics
    unsigned csub = (unsigned)(E / (K * NSUB)) + 1024u;
    csub = (csub + 63u) & ~63u;

    // layout: [recs: K*NSUB*csub*8] [slices: NSLICE*N*16] [xh: N*8] [acc4: N*16] [cursor] [consts]
    size_t rec_bytes = (size_t)K * NSUB * csub * sizeof(uint2);
    size_t sp_slices = rec_bytes;
    size_t sp_xh     = sp_slices + (size_t)NSLICE * N * sizeof(uint4);
    size_t sp_acc    = (sp_xh + (size_t)N * sizeof(uint2) + 15) & ~(size_t)15;
    size_t sp_cur    = sp_acc + (size_t)N * sizeof(uint4);
    size_t sp_const  = (sp_cur + (size_t)NSUB * KMAX * sizeof(unsigned) + 15) & ~(size_t)15;
    size_t need      = sp_const + 32;

    if (K <= KMAX && ws_size >= need) {
        uint2*    recs   = (uint2*)   d_ws;
        uint4*    slices = (uint4*)   ((char*)d_ws + sp_slices);
        uint2*    xh     = (uint2*)   ((char*)d_ws + sp_xh);
        unsigned* acc4   = (unsigned*)((char*)d_ws + sp_acc);
        unsigned* cursor = (unsigned*)((char*)d_ws + sp_cur);
        float*    consts = (float*)   ((char*)d_ws + sp_const);

        repack_h_kernel<<<(N + 255) / 256, 256, 0, stream>>>(
            x, xh, N, Wp1, bp1, Wp2, consts, (uint4*)acc4, cursor, K);
        fused5_kernel<<<nblk, TPB1, 0, stream>>>(
            xh, ei, Wp1, bp1, Wp2, consts, cursor, acc4, recs, E, K, csub);
        reduce5_kernel<<<K * NSLICE, 256, 0, stream>>>(recs, cursor, slices, N, K, csub);
        node_merge_kernel<<<(N + 255) / 256, 256, 0, stream>>>(
            x, vel_norm, vel, W1, b1, W2, b2, slices, (const uint4*)acc4,
            (float*)d_out, N);
    } else {
        float* acc    = (float*)d_ws;
        float* consts = (float*)((char*)d_ws + (size_t)N * sizeof(float4));
        hipMemsetAsync(d_ws, 0, (size_t)N * sizeof(float4) + 32, stream);
        precompute_kernel<<<1, 64, 0, stream>>>(Wp1, bp1, Wp2, consts);
        edge_atomic_kernel<<<(E + 255) / 256, 256, 0, stream>>>(x, ei, Wp1, bp1, Wp2,
                                                                consts, acc, E);
        node_kernel<<<(N + 255) / 256, 256, 0, stream>>>(x, vel_norm, vel, W1, b1, W2, b2,
                                                         (const float4*)acc, (float*)d_out, N, 1);
    }
}